// Round 7
// baseline (74.646 us; speedup 1.0000x reference)
//
#include <hip/hip_runtime.h>
#include <stdint.h>

typedef __attribute__((ext_vector_type(2))) float f32x2;
typedef __attribute__((ext_vector_type(4))) float f32x4;
typedef __attribute__((ext_vector_type(8))) short bf16x8;

static constexpr int N_ = 4, C_ = 256, HW_ = 4096;
static constexpr int CO_ = 256, KTAP = 9, KK = 2304;  // KK = C_*KTAP
static constexpr int NST = 36;                        // K-steps of 64
static constexpr int A_PLANE = 16 * 64 * 16;          // one BK=32 plane of A: 16KB

static constexpr size_t NHWC_BYTES = (size_t)N_ * HW_ * C_ * 2;  // 8 MB
static constexpr size_t ABF_OFF    = NHWC_BYTES;
static constexpr size_t ABF_BYTES  = (size_t)72 * A_PLANE;       // 1.18 MB

__device__ inline unsigned f2bf(float f) {
  unsigned u = __builtin_bit_cast(unsigned, f);
  unsigned r = u + 0x7FFFu + ((u >> 16) & 1u);
  return r >> 16;
}
__device__ inline float asf(unsigned u) { return __builtin_bit_cast(float, u); }

// ---------------- merged prep: NCHW->NHWC bf16 (blocks 0..1023) +
//                  filter -> fragment-major bf16 (blocks 1024..1279) ----------
__global__ __launch_bounds__(256) void k_prep(const float* __restrict__ in,
                                              const float* __restrict__ filt,
                                              unsigned short* __restrict__ nhwc,
                                              unsigned short* __restrict__ abf2) {
  int b = blockIdx.x;
  int t = threadIdx.x;
  if (b < 1024) {
    __shared__ float tile[64][65];
    int n = b >> 8, cg = (b >> 6) & 3, hwg = b & 63;
    int c0 = cg * 64, hw0 = hwg * 64;
    int col = t & 63, r0 = t >> 6;
#pragma unroll
    for (int i = 0; i < 16; ++i) {
      int row = r0 + i * 4;
      tile[row][col] = in[(size_t)(n * C_ + c0 + row) * HW_ + hw0 + col];
    }
    __syncthreads();
    int pr = t >> 2, cc0 = (t & 3) * 16;
    unsigned us[8];
#pragma unroll
    for (int i = 0; i < 8; ++i) {
      unsigned lo = f2bf(tile[cc0 + 2 * i][pr]);
      unsigned hi = f2bf(tile[cc0 + 2 * i + 1][pr]);
      us[i] = lo | (hi << 16);
    }
    unsigned* dst = (unsigned*)(nhwc + (size_t)(n * HW_ + hw0 + pr) * C_ + c0 + cc0);
    ((uint4*)dst)[0] = make_uint4(us[0], us[1], us[2], us[3]);
    ((uint4*)dst)[1] = make_uint4(us[4], us[5], us[6], us[7]);
  } else {
    // abf2[((s32*16 + rb)*64 + lane)*8 + j]: s32 = tap*8+(c>>5), rb=o>>4,
    // lane = ((c>>3)&3)*16 + (o&15), j = c&7.
    int gid = (b - 1024) * 256 + t;
    int o = gid >> 8, c = gid & 255;
    const float* f = filt + (size_t)(o * C_ + c) * KTAP;
    int rb = o >> 4;
    int lane = ((c >> 3) & 3) * 16 + (o & 15);
    int j = c & 7;
#pragma unroll
    for (int tap = 0; tap < KTAP; ++tap) {
      int s32 = tap * 8 + (c >> 5);
      abf2[((size_t)(s32 * 16 + rb) * 64 + lane) * 8 + j] = (unsigned short)f2bf(f[tap]);
    }
  }
}

struct GB2 { uint4 g[8]; f32x4 w; };  // depth bank: 4 corners x 2 quads (16 ch)
struct AF  { bf16x8 f[4]; };          // (mi,k) frags: f[mi*2+k]

__device__ __forceinline__ f32x2 unpk(unsigned u) {
  return (f32x2){asf(u << 16), asf(u & 0xffff0000u)};
}

// bilinear combine: 8 channels (one uint4 per corner) -> 16B into LDS
__device__ __forceinline__ void buildB8p(const uint4& g0, const uint4& g1,
                                         const uint4& g2, const uint4& g3,
                                         f32x4 w, char* dst) {
  f32x2 r0 = w.x * unpk(g0.x) + w.y * unpk(g1.x) + w.z * unpk(g2.x) + w.w * unpk(g3.x);
  f32x2 r1 = w.x * unpk(g0.y) + w.y * unpk(g1.y) + w.z * unpk(g2.y) + w.w * unpk(g3.y);
  f32x2 r2 = w.x * unpk(g0.z) + w.y * unpk(g1.z) + w.z * unpk(g2.z) + w.w * unpk(g3.z);
  f32x2 r3 = w.x * unpk(g0.w) + w.y * unpk(g1.w) + w.z * unpk(g2.w) + w.w * unpk(g3.w);
  unsigned o0, o1, o2, o3;
  asm("v_cvt_pk_bf16_f32 %0, %1, %2" : "=v"(o0) : "v"(r0.x), "v"(r0.y));
  asm("v_cvt_pk_bf16_f32 %0, %1, %2" : "=v"(o1) : "v"(r1.x), "v"(r1.y));
  asm("v_cvt_pk_bf16_f32 %0, %1, %2" : "=v"(o2) : "v"(r2.x), "v"(r2.y));
  asm("v_cvt_pk_bf16_f32 %0, %1, %2" : "=v"(o3) : "v"(r3.x), "v"(r3.y));
  *(uint4*)dst = make_uint4(o0, o1, o2, o3);
}

#define MFMA_BF16 __builtin_amdgcn_mfma_f32_16x16x32_bf16

// One BK=64 step. Consumers: prefetch A(S+1), read B(S) from Bl[RDP], 16 MFMA.
// Producers: refresh records at tap boundary, issue gathers g(S+2) into GISS,
// build B(S+1) from GCON into Bl[WRP]. One barrier per step.
#define PIPE(S, RDP, WRP, GCON, GISS, AC, AN)                                  \
  do {                                                                         \
    if (cons) {                                                                \
      int s1_ = (S) + 1 < NST ? (S) + 1 : NST - 1;                             \
      const char* ab_ = aoff0 + (size_t)(2 * s1_) * A_PLANE;                   \
      AN.f[0] = *(const bf16x8*)(ab_);                                         \
      AN.f[1] = *(const bf16x8*)(ab_ + A_PLANE);                               \
      AN.f[2] = *(const bf16x8*)(ab_ + 1024);                                  \
      AN.f[3] = *(const bf16x8*)(ab_ + 1024 + A_PLANE);                        \
      const char* bb_ = (const char*)&Bl[0][0] + (RDP) * 8192;                 \
      bf16x8 b0_ = *(const bf16x8*)(bb_ + bo[0][0]);                           \
      bf16x8 b1_ = *(const bf16x8*)(bb_ + bo[1][0]);                           \
      bf16x8 b2_ = *(const bf16x8*)(bb_ + bo[2][0]);                           \
      bf16x8 b3_ = *(const bf16x8*)(bb_ + bo[3][0]);                           \
      __builtin_amdgcn_s_setprio(1);                                           \
      acc[0][0] = MFMA_BF16(AC.f[0], b0_, acc[0][0], 0, 0, 0);                 \
      acc[1][0] = MFMA_BF16(AC.f[2], b0_, acc[1][0], 0, 0, 0);                 \
      acc[0][1] = MFMA_BF16(AC.f[0], b1_, acc[0][1], 0, 0, 0);                 \
      acc[1][1] = MFMA_BF16(AC.f[2], b1_, acc[1][1], 0, 0, 0);                 \
      acc[0][2] = MFMA_BF16(AC.f[0], b2_, acc[0][2], 0, 0, 0);                 \
      acc[1][2] = MFMA_BF16(AC.f[2], b2_, acc[1][2], 0, 0, 0);                 \
      acc[0][3] = MFMA_BF16(AC.f[0], b3_, acc[0][3], 0, 0, 0);                 \
      acc[1][3] = MFMA_BF16(AC.f[2], b3_, acc[1][3], 0, 0, 0);                 \
      __builtin_amdgcn_s_setprio(0);                                           \
      bf16x8 b4_ = *(const bf16x8*)(bb_ + bo[0][1]);                           \
      bf16x8 b5_ = *(const bf16x8*)(bb_ + bo[1][1]);                           \
      bf16x8 b6_ = *(const bf16x8*)(bb_ + bo[2][1]);                           \
      bf16x8 b7_ = *(const bf16x8*)(bb_ + bo[3][1]);                           \
      __builtin_amdgcn_s_setprio(1);                                           \
      acc[0][0] = MFMA_BF16(AC.f[1], b4_, acc[0][0], 0, 0, 0);                 \
      acc[1][0] = MFMA_BF16(AC.f[3], b4_, acc[1][0], 0, 0, 0);                 \
      acc[0][1] = MFMA_BF16(AC.f[1], b5_, acc[0][1], 0, 0, 0);                 \
      acc[1][1] = MFMA_BF16(AC.f[3], b5_, acc[1][1], 0, 0, 0);                 \
      acc[0][2] = MFMA_BF16(AC.f[1], b6_, acc[0][2], 0, 0, 0);                 \
      acc[1][2] = MFMA_BF16(AC.f[3], b6_, acc[1][2], 0, 0, 0);                 \
      acc[0][3] = MFMA_BF16(AC.f[1], b7_, acc[0][3], 0, 0, 0);                 \
      acc[1][3] = MFMA_BF16(AC.f[3], b7_, acc[1][3], 0, 0, 0);                 \
      __builtin_amdgcn_s_setprio(0);                                           \
    } else {                                                                   \
      int s2_ = (S) + 2 < NST ? (S) + 2 : NST - 1;                             \
      if ((s2_ & 3) == 0) {                                                    \
        int tp_ = s2_ >> 2;                                                    \
        uint4 ra_ = *(const uint4*)&recA[(tp_ * 64 + p_b) * 4];                \
        wS = *(const f32x4*)&recW[(tp_ * 64 + p_b) * 4];                       \
        vS.x = ra_.x + kq32; vS.y = ra_.y + kq32;                              \
        vS.z = ra_.z + kq32; vS.w = ra_.w + kq32;                              \
      }                                                                        \
      unsigned co_ = (unsigned)((s2_ & 3) * 128);                              \
      GISS.g[0] = *(const uint4*)(nb_u + vS.x + co_);                          \
      GISS.g[1] = *(const uint4*)(nb_u + vS.x + co_ + 16);                     \
      GISS.g[2] = *(const uint4*)(nb_u + vS.y + co_);                          \
      GISS.g[3] = *(const uint4*)(nb_u + vS.y + co_ + 16);                     \
      GISS.g[4] = *(const uint4*)(nb_u + vS.z + co_);                          \
      GISS.g[5] = *(const uint4*)(nb_u + vS.z + co_ + 16);                     \
      GISS.g[6] = *(const uint4*)(nb_u + vS.w + co_);                          \
      GISS.g[7] = *(const uint4*)(nb_u + vS.w + co_ + 16);                     \
      GISS.w = wS;                                                             \
      __builtin_amdgcn_sched_barrier(0);                                       \
      buildB8p(GCON.g[0], GCON.g[2], GCON.g[4], GCON.g[6], GCON.w,             \
               bwp0 + (WRP) * 8192);                                           \
      buildB8p(GCON.g[1], GCON.g[3], GCON.g[5], GCON.g[7], GCON.w,             \
               bwp1 + (WRP) * 8192);                                           \
      asm volatile("s_waitcnt lgkmcnt(0)" ::: "memory");                       \
    }                                                                          \
    asm volatile("" ::: "memory");                                             \
    __builtin_amdgcn_s_barrier();                                              \
    asm volatile("" ::: "memory");                                             \
  } while (0)

// ---------------- fused sample + GEMM (producer/consumer, BK=64) -------------
// 256 blocks (one per output row) x 768 threads (12 waves, 3/SIMD):
//   waves 0-7  = consumers: wave tile 32 Cout x 64 px, 16 MFMA/step
//   waves 8-11 = producers: 256 thr = 64 px x 4 kq (16 ch each), depth-2 banks
// B LDS per step-buffer (8KB): plane p=ch>>3 (0..7): addr = p*1024 +
//   ((px + 5p)&63)*16  -> bank-minimal for ds_read_b128 and ds_write_b128.
__global__ __launch_bounds__(768, 3) void k_dcn_gemm(const unsigned short* __restrict__ nhwc,
                                                     const unsigned short* __restrict__ abf2,
                                                     const float* __restrict__ offs,
                                                     const float* __restrict__ msk,
                                                     float* __restrict__ out) {
  __shared__ __align__(16) unsigned short Bl[2][4096];  // 2 x 8KB step buffers
  __shared__ float recW[KTAP * 64 * 4];
  __shared__ unsigned recA[KTAP * 64 * 4];

  int bid = blockIdx.x;
  int b = ((bid & 7) << 5) | (bid >> 3);  // XCD-aware swizzle (bijective, 256%8==0)
  int n = b >> 6;
  int ho = b & 63;
  int hw0 = ho << 6;
  int t = threadIdx.x;

  // --- per (pixel, tap) sampling records ---
  for (int r = t; r < 576; r += 768) {
    int pl = r / 9;
    int tap = r - pl * 9;
    int hw = hw0 + pl;
    float dy = offs[(size_t)(n * 18 + 2 * tap) * HW_ + hw];
    float dx = offs[(size_t)(n * 18 + 2 * tap + 1) * HW_ + hw];
    float mk = msk[(size_t)(n * 9 + tap) * HW_ + hw];
    float y = (float)(ho - 1 + tap / 3) + dy;
    float x = (float)(pl - 1 + tap % 3) + dx;
    float fy = floorf(y), fx = floorf(x);
    float ly = y - fy, lx = x - fx;
    int y0 = (int)fy, x0 = (int)fx;
    int y1 = y0 + 1, x1 = x0 + 1;
    float vy0 = (y0 >= 0 && y0 < 64) ? 1.f : 0.f;
    float vy1 = (y1 >= 0 && y1 < 64) ? 1.f : 0.f;
    float vx0 = (x0 >= 0 && x0 < 64) ? 1.f : 0.f;
    float vx1 = (x1 >= 0 && x1 < 64) ? 1.f : 0.f;
    int y0c = min(max(y0, 0), 63), y1c = min(max(y1, 0), 63);
    int x0c = min(max(x0, 0), 63), x1c = min(max(x1, 0), 63);
    int base = (tap * 64 + pl) * 4;
    recW[base + 0] = (1.f - ly) * (1.f - lx) * mk * vy0 * vx0;
    recW[base + 1] = (1.f - ly) * lx * mk * vy0 * vx1;
    recW[base + 2] = ly * (1.f - lx) * mk * vy1 * vx0;
    recW[base + 3] = ly * lx * mk * vy1 * vx1;
    recA[base + 0] = (unsigned)((y0c * 64 + x0c) * 512);
    recA[base + 1] = (unsigned)((y0c * 64 + x1c) * 512);
    recA[base + 2] = (unsigned)((y1c * 64 + x0c) * 512);
    recA[base + 3] = (unsigned)((y1c * 64 + x1c) * 512);
  }
  __syncthreads();

  int lane = t & 63, wv = t >> 6;
  bool cons = wv < 8;

  // consumer addressing: wave wv owns Cout [wv*32, wv*32+32) -> rb = 2wv, 2wv+1
  const char* aoff0 = (const char*)abf2 + ((wv * 2) * 64 + lane) * 16;
  int q_r = lane >> 4;
  int pxl = lane & 15;
  int bo[4][2];
#pragma unroll
  for (int ni = 0; ni < 4; ++ni)
#pragma unroll
    for (int h = 0; h < 2; ++h) {
      int p = h * 4 + q_r;
      bo[ni][h] = p * 1024 + (((pxl + 16 * ni) + 5 * p) & 63) * 16;
    }

  // producer addressing (threads 512..767): thread = (px 0..63, kq 0..3), 16ch
  int pid = t - 512;
  int p_b = (pid >> 2) & 63;
  int kq = pid & 3;
  unsigned kq32 = (unsigned)(kq * 32);
  const char* nb_u = (const char*)nhwc + (size_t)n * HW_ * C_ * 2;
  int pl0 = 2 * kq, pl1 = 2 * kq + 1;
  char* bwp0 = (char*)&Bl[0][0] + pl0 * 1024 + ((p_b + 5 * pl0) & 63) * 16;
  char* bwp1 = (char*)&Bl[0][0] + pl1 * 1024 + ((p_b + 5 * pl1) & 63) * 16;

  f32x4 acc[2][4];
#pragma unroll
  for (int mi = 0; mi < 2; ++mi)
#pragma unroll
    for (int ni = 0; ni < 4; ++ni) acc[mi][ni] = (f32x4){0.f, 0.f, 0.f, 0.f};

  GB2 gA, gB;
  AF aC, aN;
  uint4 vS;
  f32x4 wS;

  // --- prologue: g(0)->gA, g(1)->gB, A(0); build B(0) into buf0 ---
  if (cons) {
    aC.f[0] = *(const bf16x8*)(aoff0);
    aC.f[1] = *(const bf16x8*)(aoff0 + A_PLANE);
    aC.f[2] = *(const bf16x8*)(aoff0 + 1024);
    aC.f[3] = *(const bf16x8*)(aoff0 + 1024 + A_PLANE);
  } else {
    uint4 ra0 = *(const uint4*)&recA[p_b * 4];  // tap 0
    wS = *(const f32x4*)&recW[p_b * 4];
    vS.x = ra0.x + kq32; vS.y = ra0.y + kq32;
    vS.z = ra0.z + kq32; vS.w = ra0.w + kq32;
    gA.g[0] = *(const uint4*)(nb_u + vS.x);
    gA.g[1] = *(const uint4*)(nb_u + vS.x + 16);
    gA.g[2] = *(const uint4*)(nb_u + vS.y);
    gA.g[3] = *(const uint4*)(nb_u + vS.y + 16);
    gA.g[4] = *(const uint4*)(nb_u + vS.z);
    gA.g[5] = *(const uint4*)(nb_u + vS.z + 16);
    gA.g[6] = *(const uint4*)(nb_u + vS.w);
    gA.g[7] = *(const uint4*)(nb_u + vS.w + 16);
    gA.w = wS;
    gB.g[0] = *(const uint4*)(nb_u + vS.x + 128);
    gB.g[1] = *(const uint4*)(nb_u + vS.x + 144);
    gB.g[2] = *(const uint4*)(nb_u + vS.y + 128);
    gB.g[3] = *(const uint4*)(nb_u + vS.y + 144);
    gB.g[4] = *(const uint4*)(nb_u + vS.z + 128);
    gB.g[5] = *(const uint4*)(nb_u + vS.z + 144);
    gB.g[6] = *(const uint4*)(nb_u + vS.w + 128);
    gB.g[7] = *(const uint4*)(nb_u + vS.w + 144);
    gB.w = wS;
    buildB8p(gA.g[0], gA.g[2], gA.g[4], gA.g[6], gA.w, bwp0);
    buildB8p(gA.g[1], gA.g[3], gA.g[5], gA.g[7], gA.w, bwp1);
    asm volatile("s_waitcnt lgkmcnt(0)" ::: "memory");
  }
  asm volatile("" ::: "memory");
  __builtin_amdgcn_s_barrier();
  asm volatile("" ::: "memory");

  // --- main loop: 36 BK=64 steps, one barrier per step ---
  for (int s = 0; s < NST; s += 2) {
    PIPE(s,     0, 1, gB, gA, aC, aN);
    PIPE(s + 1, 1, 0, gA, gB, aN, aC);
  }

  // --- epilogue (consumers only): D row = Cout, col = px ---
  if (cons) {
    float* ob = out + (size_t)n * CO_ * HW_ + hw0;
#pragma unroll
    for (int mi = 0; mi < 2; ++mi)
#pragma unroll
      for (int ni = 0; ni < 4; ++ni)
#pragma unroll
        for (int jj = 0; jj < 4; ++jj) {
          int o = wv * 32 + mi * 16 + (lane >> 4) * 4 + jj;
          int hw = ni * 16 + (lane & 15);
          ob[(size_t)o * HW_ + hw] = acc[mi][ni][jj];
        }
  }
}

extern "C" void kernel_launch(void* const* d_in, const int* in_sizes, int n_in,
                              void* d_out, int out_size, void* d_ws, size_t ws_size,
                              hipStream_t stream) {
  const float* inp  = (const float*)d_in[0];
  const float* filt = (const float*)d_in[1];
  const float* offs = (const float*)d_in[2];
  const float* msk  = (const float*)d_in[3];
  float* out = (float*)d_out;
  if (ws_size < ABF_OFF + ABF_BYTES) return;  // ~9.6 MB scratch
  unsigned short* nhwc = (unsigned short*)d_ws;
  unsigned short* abf2 = (unsigned short*)((char*)d_ws + ABF_OFF);

  k_prep<<<1280, 256, 0, stream>>>(inp, filt, nhwc, abf2);
  k_dcn_gemm<<<256, 768, 0, stream>>>(nhwc, abf2, offs, msk, out);
}